// Round 4
// baseline (946.967 us; speedup 1.0000x reference)
//
#include <hip/hip_runtime.h>

#define B_SZ 4096
#define D_SZ 1024
#define K_SZ 32
#define NT   16          // K-depth steps of 64

typedef _Float16 h16x8 __attribute__((ext_vector_type(8)));
typedef float f32x16 __attribute__((ext_vector_type(16)));
typedef float f32x4 __attribute__((ext_vector_type(4)));
typedef float f32x2 __attribute__((ext_vector_type(2)));
typedef unsigned int u32x2 __attribute__((ext_vector_type(2)));
typedef unsigned int u32x4 __attribute__((ext_vector_type(4)));
typedef unsigned short u16x4 __attribute__((ext_vector_type(4)));

// async global->LDS, 16B per lane (wave-uniform LDS base + lane*16)
#define GLOAD16(gp, sp) __builtin_amdgcn_global_load_lds( \
    (const __attribute__((address_space(1))) void*)(gp),  \
    (__attribute__((address_space(3))) void*)(sp), 16, 0, 0)

// fp32 -> fp16 hi + fp16 lo*2^11 (lo scaled to stay normal)
__device__ __forceinline__ void split1(float x, _Float16& h, _Float16& l) {
    h = (_Float16)x;
    l = (_Float16)((x - (float)h) * 2048.0f);
}

// ---------------- prepass: W[k][d][e] f32 -> Wt_h/Wt_l[k][e][d] fp16 ----------------
__global__ __launch_bounds__(256)
void ntl_prep_w(const float* __restrict__ W,
                _Float16* __restrict__ Wh, _Float16* __restrict__ Wl) {
    __shared__ float tile[64 * 69];
    const int bid = blockIdx.x;
    const int k  = bid >> 8;
    const int d0 = ((bid >> 4) & 15) << 6;
    const int e0 = (bid & 15) << 6;
    const int t  = threadIdx.x;
    const int r  = t >> 4;
    const int c4 = (t & 15) << 2;

    const float* src = W + ((size_t)k * D_SZ + d0) * D_SZ + e0;
    #pragma unroll
    for (int p = 0; p < 4; ++p) {
        f32x4 v = *(const f32x4*)(src + (size_t)(p * 16 + r) * D_SZ + c4);
        float* dst = &tile[(p * 16 + r) * 69 + c4];
        dst[0] = v[0]; dst[1] = v[1]; dst[2] = v[2]; dst[3] = v[3];
    }
    __syncthreads();
    #pragma unroll
    for (int p = 0; p < 4; ++p) {
        const int e = p * 16 + r;
        u16x4 hh, ll;
        #pragma unroll
        for (int q = 0; q < 4; ++q) {
            float v = tile[(c4 + q) * 69 + e];
            _Float16 h, l;
            split1(v, h, l);
            hh[q] = __builtin_bit_cast(unsigned short, h);
            ll[q] = __builtin_bit_cast(unsigned short, l);
        }
        const size_t o = ((size_t)k * D_SZ + e0 + e) * D_SZ + d0 + c4;
        *(u16x4*)(Wh + o) = hh;
        *(u16x4*)(Wl + o) = ll;
    }
}

// ---------------- prepass: e1 f32 -> e1_h/e1_l fp16 ----------------
__global__ __launch_bounds__(256)
void ntl_prep_e(const float* __restrict__ e1,
                _Float16* __restrict__ eh, _Float16* __restrict__ el) {
    const size_t i = ((size_t)blockIdx.x * 256 + threadIdx.x) * 4;
    f32x4 v = *(const f32x4*)(e1 + i);
    u16x4 hh, ll;
    #pragma unroll
    for (int q = 0; q < 4; ++q) {
        _Float16 h, l;
        split1(v[q], h, l);
        hh[q] = __builtin_bit_cast(unsigned short, h);
        ll[q] = __builtin_bit_cast(unsigned short, l);
    }
    *(u16x4*)(eh + i) = hh;
    *(u16x4*)(el + i) = ll;
}

// ---------------- main bilinear: 256x128 tile, one k, 8 waves ----------
// LDS (128KB): Ah [0,32K) Al [32K,64K) | Bset0 [64K,96K) Bset1 [96K,128K)
//   A: 256 rows x 128B, XOR slot-swizzle (write-side + read-side, source linear)
//   B: per set {Bh 16K, Bl 16K}, 128 rows x 128B, gload_lds linear dest,
//      pre-swizzled GLOBAL source column (rule #21).
// Pipeline: B(t+1) gload_lds + A(t+1) global->reg issued before compute(t);
// vmcnt(0) drain at top of iter t+1 (one full MFMA phase of slack).
__global__ __launch_bounds__(512, 2)
void ntl_bilinear4(const _Float16* __restrict__ eh, const _Float16* __restrict__ el,
                   const _Float16* __restrict__ Wh, const _Float16* __restrict__ Wl,
                   const float* __restrict__ e2, float* __restrict__ out) {
    __shared__ __align__(16) char lds[131072];

    const int bid   = blockIdx.x;
    const int xcd   = bid & 7;          // XCD round-robin pinning
    const int idx   = bid >> 3;         // 0..511
    const int e_t   = idx & 7;          // 8 e-tiles
    const int b_sub = (idx >> 3) & 1;   // 2 b-tiles per XCD
    const int k     = idx >> 4;         // 0..31, slowest within XCD
    const int b0    = (xcd * 2 + b_sub) * 256;
    const int e0    = e_t * 128;

    const int t    = threadIdx.x;
    const int l    = t & 63;
    const int w    = t >> 6;            // 0..7
    const int wrow = (w >> 1) * 64;     // 0,64,128,192
    const int wcol = (w & 1) * 64;      // 0,64
    const int l31  = l & 31;
    const int h5   = l >> 5;
    const int srow = l >> 3;            // 0..7
    const int sl   = l & 7;

    f32x16 acc1[2][2];   // hi*hi
    f32x16 acc2[2][2];   // hi*lo' + lo'*hi  (scale 2^11)
    #pragma unroll
    for (int m = 0; m < 2; ++m)
        #pragma unroll
        for (int n = 0; n < 2; ++n) {
            #pragma unroll
            for (int j = 0; j < 16; ++j) { acc1[m][n][j] = 0.f; acc2[m][n][j] = 0.f; }
        }

    // A: reg-staged, LINEAR global source (swizzle applied at ds_write + ds_read)
    const size_t arow = (size_t)(b0 + w * 32 + srow) * D_SZ + sl * 8;
    const _Float16* gAh = eh + arow;
    const _Float16* gAl = el + arow;
    // A ds_write dest (swizzled): row_local = w*32 + i*8 + srow, slot = sl ^ srow
    const int awOff = (w * 32 + srow) * 128 + ((sl ^ srow) << 4);

    // B: gload_lds, pre-swizzled source column
    const int gslot = sl ^ srow;
    const _Float16* gB = (w < 4 ? Wh : Wl) +
        ((size_t)k * D_SZ + e0 + (w & 3) * 32 + srow) * D_SZ + gslot * 8;
    const int bOff = (w >= 4 ? 16384 : 0) + (w & 3) * 4096;   // within B set

    u32x4 arH[4], arL[4];

    // ---- prologue: issue B(0) + A(0) ----
    {
        char* bset = lds + 65536;
        #pragma unroll
        for (int i = 0; i < 4; ++i)
            GLOAD16(gB + (size_t)i * 8 * D_SZ, bset + bOff + i * 1024);
        #pragma unroll
        for (int i = 0; i < 4; ++i) {
            arH[i] = *(const u32x4*)(gAh + (size_t)i * 8 * D_SZ);
            arL[i] = *(const u32x4*)(gAl + (size_t)i * 8 * D_SZ);
        }
    }

    for (int kt = 0; kt < NT; ++kt) {
        if (kt) {
            __builtin_amdgcn_s_barrier();            // readers of A(kt-1)/B(kt-1) done
            __builtin_amdgcn_sched_barrier(0);
        }
        asm volatile("s_waitcnt vmcnt(0)" ::: "memory");   // A(kt) regs + B(kt) landed
        __builtin_amdgcn_sched_barrier(0);

        // ds_write A(kt) regs -> swizzled LDS
        #pragma unroll
        for (int i = 0; i < 4; ++i) {
            *(u32x4*)(lds + awOff + i * 1024)         = arH[i];
            *(u32x4*)(lds + 32768 + awOff + i * 1024) = arL[i];
        }

        // issue next tile's loads (stay in flight across barrier + compute)
        if (kt + 1 < NT) {
            const size_t dn = (size_t)(kt + 1) * 64;
            char* bset = lds + 65536 + (((kt + 1) & 1) << 15);
            #pragma unroll
            for (int i = 0; i < 4; ++i)
                GLOAD16(gB + (size_t)i * 8 * D_SZ + dn, bset + bOff + i * 1024);
            #pragma unroll
            for (int i = 0; i < 4; ++i) {
                arH[i] = *(const u32x4*)(gAh + (size_t)i * 8 * D_SZ + dn);
                arL[i] = *(const u32x4*)(gAl + (size_t)i * 8 * D_SZ + dn);
            }
        }

        asm volatile("s_waitcnt lgkmcnt(0)" ::: "memory");  // own ds_writes done
        __builtin_amdgcn_sched_barrier(0);
        __builtin_amdgcn_s_barrier();                        // all staging visible
        __builtin_amdgcn_sched_barrier(0);

        // ---- compute: 3-pass fp16 split, 32x32x16 MFMA ----
        const char* Bh_ = lds + 65536 + ((kt & 1) << 15);
        const char* Bl_ = Bh_ + 16384;

        #pragma unroll
        for (int ks = 0; ks < 4; ++ks) {
            h16x8 ah[2], al[2], bh[2], bl[2];
            #pragma unroll
            for (int m = 0; m < 2; ++m) {
                const int r = wrow + m * 32 + l31;
                const int off = r * 128 + (((ks * 2 + h5) ^ (r & 7)) << 4);
                ah[m] = *(const h16x8*)(lds + off);
                al[m] = *(const h16x8*)(lds + 32768 + off);
            }
            #pragma unroll
            for (int n = 0; n < 2; ++n) {
                const int r = wcol + n * 32 + l31;
                const int off = r * 128 + (((ks * 2 + h5) ^ (r & 7)) << 4);
                bh[n] = *(const h16x8*)(Bh_ + off);
                bl[n] = *(const h16x8*)(Bl_ + off);
            }
            #pragma unroll
            for (int m = 0; m < 2; ++m)
                #pragma unroll
                for (int n = 0; n < 2; ++n) {
                    acc1[m][n] = __builtin_amdgcn_mfma_f32_32x32x16_f16(ah[m], bh[n], acc1[m][n], 0, 0, 0);
                    acc2[m][n] = __builtin_amdgcn_mfma_f32_32x32x16_f16(ah[m], bl[n], acc2[m][n], 0, 0, 0);
                    acc2[m][n] = __builtin_amdgcn_mfma_f32_32x32x16_f16(al[m], bh[n], acc2[m][n], 0, 0, 0);
                }
        }
    }

    // ---- epilogue: T .* e2 over this block's 128 e-cols ----
    // 32x32 C/D layout (m74/m101): col = lane&31, row = (rg&3) + 8*(rg>>2) + 4*(lane>>5)
    float rsum[2][16];
    #pragma unroll
    for (int m = 0; m < 2; ++m)
        #pragma unroll
        for (int rg = 0; rg < 16; ++rg) rsum[m][rg] = 0.f;

    #pragma unroll
    for (int m = 0; m < 2; ++m) {
        #pragma unroll
        for (int n = 0; n < 2; ++n) {
            #pragma unroll
            for (int rg = 0; rg < 16; ++rg) {
                const int rowl = wrow + m * 32 + (rg & 3) + 8 * (rg >> 2) + 4 * h5;
                const int col  = e0 + wcol + n * 32 + l31;
                float tv = acc1[m][n][rg] + acc2[m][n][rg] * (1.0f / 2048.0f);
                rsum[m][rg] += tv * e2[(size_t)(b0 + rowl) * D_SZ + col];
            }
        }
    }

    #pragma unroll
    for (int m = 0; m < 2; ++m) {
        #pragma unroll
        for (int rg = 0; rg < 16; ++rg) {
            float v = rsum[m][rg];
            v += __shfl_xor(v, 1, 32);
            v += __shfl_xor(v, 2, 32);
            v += __shfl_xor(v, 4, 32);
            v += __shfl_xor(v, 8, 32);
            v += __shfl_xor(v, 16, 32);
            if (l31 == 0) {
                const int rowl = wrow + m * 32 + (rg & 3) + 8 * (rg >> 2) + 4 * h5;
                atomicAdd(out + (size_t)k * B_SZ + b0 + rowl, v);
            }
        }
    }
}

// ================= fallback path (round-1 bilinear, used if ws too small) =================
__device__ __forceinline__ int swz_fb(int row, int byte_in_row) {
    int slot = byte_in_row >> 4;
    int in   = byte_in_row & 15;
    return row * 128 + (((slot ^ (row & 7)) << 4) | in);
}
__device__ __forceinline__ void split_fb(float x, unsigned short& h, unsigned short& l) {
    _Float16 hf = (_Float16)x;
    float hff = (float)hf;
    _Float16 lf = (_Float16)((x - hff) * 2048.0f);
    h = __builtin_bit_cast(unsigned short, hf);
    l = __builtin_bit_cast(unsigned short, lf);
}
__global__ __launch_bounds__(256, 2)
void ntl_bilinear_fb(const float* __restrict__ e1, const float* __restrict__ e2,
                     const float* __restrict__ W, float* __restrict__ out) {
    __shared__ __align__(16) char smem[65536];
    char* const Ah = smem;
    char* const Al = smem + 16384;
    char* const Bh = smem + 32768;
    char* const Bl = smem + 49152;
    const int bid = blockIdx.x;
    const int k   = bid >> 8;
    const int rem = bid & 255;
    const int b0  = (rem >> 3) * 128;
    const int e0  = (rem & 7) * 128;
    const int t  = threadIdx.x;
    const int l  = t & 63;
    const int w  = t >> 6;
    const int wr = (w >> 1) * 64;
    const int wc = (w & 1) * 64;
    const int lrow = l & 15;
    const int lq   = l >> 4;
    f32x4 acc1[4][4], acc2[4][4];
    #pragma unroll
    for (int m = 0; m < 4; ++m)
        #pragma unroll
        for (int n = 0; n < 4; ++n) {
            acc1[m][n] = f32x4{0.f, 0.f, 0.f, 0.f};
            acc2[m][n] = f32x4{0.f, 0.f, 0.f, 0.f};
        }
    const int sa_row = t >> 4;
    const int sa_cg  = (t & 15) * 4;
    const int sb_e   = t & 127;
    const int sb_dg  = t >> 7;
    const float* const e1b = e1 + (size_t)b0 * D_SZ;
    const float* const wb  = W + ((size_t)k * D_SZ) * D_SZ + e0 + sb_e;
    for (int kt = 0; kt < NT; ++kt) {
        const int d0 = kt * 64;
        #pragma unroll
        for (int p = 0; p < 8; ++p) {
            const int r = sa_row + p * 16;
            f32x4 v = *(const f32x4*)(e1b + (size_t)r * D_SZ + d0 + sa_cg);
            unsigned short hh[4], ll[4];
            #pragma unroll
            for (int qq = 0; qq < 4; ++qq) split_fb(v[qq], hh[qq], ll[qq]);
            u32x2 hv = { (unsigned)hh[0] | ((unsigned)hh[1] << 16),
                         (unsigned)hh[2] | ((unsigned)hh[3] << 16) };
            u32x2 lv = { (unsigned)ll[0] | ((unsigned)ll[1] << 16),
                         (unsigned)ll[2] | ((unsigned)ll[3] << 16) };
            const int ad = swz_fb(r, sa_cg * 2);
            *(u32x2*)(Ah + ad) = hv;
            *(u32x2*)(Al + ad) = lv;
        }
        {
            const float* ws2 = wb + (size_t)(d0 + sb_dg * 32) * D_SZ;
            #pragma unroll
            for (int gg = 0; gg < 4; ++gg) {
                unsigned short hh[8], ll[8];
                #pragma unroll
                for (int i = 0; i < 8; ++i)
                    split_fb(ws2[(size_t)(gg * 8 + i) * D_SZ], hh[i], ll[i]);
                u32x4 hv = { (unsigned)hh[0] | ((unsigned)hh[1] << 16),
                             (unsigned)hh[2] | ((unsigned)hh[3] << 16),
                             (unsigned)hh[4] | ((unsigned)hh[5] << 16),
                             (unsigned)hh[6] | ((unsigned)hh[7] << 16) };
                u32x4 lv = { (unsigned)ll[0] | ((unsigned)ll[1] << 16),
                             (unsigned)ll[2] | ((unsigned)ll[3] << 16),
                             (unsigned)ll[4] | ((unsigned)ll[5] << 16),
                             (unsigned)ll[6] | ((unsigned)ll[7] << 16) };
                const int ad = swz_fb(sb_e, (sb_dg * 32 + gg * 8) * 2);
                *(u32x4*)(Bh + ad) = hv;
                *(u32x4*)(Bl + ad) = lv;
            }
        }
        __syncthreads();
        #pragma unroll
        for (int kk = 0; kk < 2; ++kk) {
            const int kb = kk * 64 + lq * 16;
            h16x8 a_h[4], a_l[4];
            #pragma unroll
            for (int m = 0; m < 4; ++m) {
                const int ad = swz_fb(wr + m * 16 + lrow, kb);
                a_h[m] = *(const h16x8*)(Ah + ad);
                a_l[m] = *(const h16x8*)(Al + ad);
            }
            #pragma unroll
            for (int n = 0; n < 4; ++n) {
                const int bd = swz_fb(wc + n * 16 + lrow, kb);
                h16x8 b_h = *(const h16x8*)(Bh + bd);
                h16x8 b_l = *(const h16x8*)(Bl + bd);
                #pragma unroll
                for (int m = 0; m < 4; ++m) {
                    acc1[m][n] = __builtin_amdgcn_mfma_f32_16x16x32_f16(a_h[m], b_h, acc1[m][n], 0, 0, 0);
                    acc2[m][n] = __builtin_amdgcn_mfma_f32_16x16x32_f16(a_h[m], b_l, acc2[m][n], 0, 0, 0);
                    acc2[m][n] = __builtin_amdgcn_mfma_f32_16x16x32_f16(a_l[m], b_h, acc2[m][n], 0, 0, 0);
                }
            }
        }
        __syncthreads();
    }
    float rsum[16];
    #pragma unroll
    for (int i = 0; i < 16; ++i) rsum[i] = 0.f;
    #pragma unroll
    for (int m = 0; m < 4; ++m) {
        #pragma unroll
        for (int n = 0; n < 4; ++n) {
            const int col = e0 + wc + n * 16 + lrow;
            #pragma unroll
            for (int j = 0; j < 4; ++j) {
                const int row = b0 + wr + m * 16 + lq * 4 + j;
                float tv = acc1[m][n][j] + acc2[m][n][j] * (1.0f / 2048.0f);
                rsum[m * 4 + j] += tv * e2[(size_t)row * D_SZ + col];
            }
        }
    }
    #pragma unroll
    for (int i = 0; i < 16; ++i) {
        float v = rsum[i];
        v += __shfl_xor(v, 1, 16);
        v += __shfl_xor(v, 2, 16);
        v += __shfl_xor(v, 4, 16);
        v += __shfl_xor(v, 8, 16);
        if (lrow == 0) {
            const int row = b0 + wr + (i >> 2) * 16 + lq * 4 + (i & 3);
            atomicAdd(out + (size_t)k * B_SZ + row, v);
        }
    }
}

// ---------------- ff / sumb / tanh ----------------
__global__ __launch_bounds__(256)
void ntl_ff(const float* __restrict__ e1, const float* __restrict__ e2,
            const float* __restrict__ V, float* __restrict__ out) {
    __shared__ float vt[32 * 258];
    const int t  = threadIdx.x;
    const int c  = t & 31;
    const int rl = t >> 5;
    const int r  = blockIdx.x * 8 + rl;
    float acc = 0.f;
    for (int j0 = 0; j0 < 2 * D_SZ; j0 += 256) {
        __syncthreads();
        #pragma unroll
        for (int i = 0; i < 32; ++i) {
            const int f = i * 256 + t;
            vt[(f & 31) * 258 + (f >> 5)] = V[(size_t)j0 * K_SZ + f];
        }
        __syncthreads();
        const float* src = (j0 < D_SZ) ? (e1 + (size_t)r * D_SZ + j0)
                                       : (e2 + (size_t)r * D_SZ + (j0 - D_SZ));
        #pragma unroll 8
        for (int jj = 0; jj < 256; jj += 2) {
            f32x2 a  = *(const f32x2*)(src + jj);
            f32x2 vv = *(const f32x2*)(&vt[c * 258 + jj]);
            acc += a[0] * vv[0] + a[1] * vv[1];
        }
    }
    out[(size_t)r * K_SZ + c] += acc;
}

__global__ void ntl_sumb(const float* __restrict__ b, float* __restrict__ ws) {
    __shared__ float red[256];
    const int t = threadIdx.x;
    red[t] = b[t] + b[t + 256] + b[t + 512] + b[t + 768];
    __syncthreads();
    for (int s = 128; s > 0; s >>= 1) {
        if (t < s) red[t] += red[t + s];
        __syncthreads();
    }
    if (t == 0) ws[0] = red[0];
}

__global__ void ntl_tanh(float* __restrict__ out, const float* __restrict__ ws) {
    const int p = blockIdx.x * 256 + threadIdx.x;
    out[p] = tanhf(out[p] + ws[0]);
}

extern "C" void kernel_launch(void* const* d_in, const int* in_sizes, int n_in,
                              void* d_out, int out_size, void* d_ws, size_t ws_size,
                              hipStream_t stream) {
    const float* e1 = (const float*)d_in[0];
    const float* e2 = (const float*)d_in[1];
    const float* W  = (const float*)d_in[2];
    const float* V  = (const float*)d_in[3];
    const float* b  = (const float*)d_in[4];
    float* out = (float*)d_out;

    const size_t WT = (size_t)K_SZ * D_SZ * D_SZ;
    const size_t ET = (size_t)B_SZ * D_SZ;
    const size_t need = (2 * WT + 2 * ET) * sizeof(_Float16) + 16;

    hipMemsetAsync(d_out, 0, (size_t)B_SZ * K_SZ * sizeof(float), stream);

    if (ws_size >= need) {
        _Float16* Wh = (_Float16*)d_ws;
        _Float16* Wl = Wh + WT;
        _Float16* eh = Wl + WT;
        _Float16* el = eh + ET;
        float* sb = (float*)(el + ET);
        ntl_sumb<<<1, 256, 0, stream>>>(b, sb);
        ntl_prep_w<<<dim3(K_SZ * 256), dim3(256), 0, stream>>>(W, Wh, Wl);
        ntl_prep_e<<<dim3((int)(ET / 1024)), dim3(256), 0, stream>>>(e1, eh, el);
        // grid: 32 k x 2 b_sub x 8 e_t x 8 xcd = 4096 blocks
        ntl_bilinear4<<<dim3(4096), dim3(512), 0, stream>>>(eh, el, Wh, Wl, e2, out);
        ntl_ff<<<dim3(B_SZ / 8), dim3(256), 0, stream>>>(e1, e2, V, out);
        ntl_tanh<<<dim3((B_SZ * K_SZ) / 256), dim3(256), 0, stream>>>(out, sb);
    } else {
        float* sb = (float*)d_ws;
        ntl_sumb<<<1, 256, 0, stream>>>(b, sb);
        ntl_bilinear_fb<<<dim3(K_SZ * 256), dim3(256), 0, stream>>>(e1, e2, W, out);
        ntl_ff<<<dim3(B_SZ / 8), dim3(256), 0, stream>>>(e1, e2, V, out);
        ntl_tanh<<<dim3((B_SZ * K_SZ) / 256), dim3(256), 0, stream>>>(out, sb);
    }
}